// Round 2
// baseline (1423.207 us; speedup 1.0000x reference)
//
#include <hip/hip_runtime.h>
#include <cstdint>

typedef __bf16 bf16;
typedef __bf16 bf16x8 __attribute__((ext_vector_type(8)));
typedef float f32x4 __attribute__((ext_vector_type(4)));

#define NEG_SLOPE 0.2f
#define BN_EPS 1e-5f
#define CHUNK 256

// ---------------- async global->LDS (16B per lane, wave-uniform LDS base) ----------------
__device__ __forceinline__ void gld_lds16(const void* g, void* l) {
  auto gp = reinterpret_cast<const __attribute__((address_space(1))) unsigned int*>(
      reinterpret_cast<uintptr_t>(g));
  auto lp = reinterpret_cast<__attribute__((address_space(3))) unsigned int*>(
      reinterpret_cast<uintptr_t>(l));
  __builtin_amdgcn_global_load_lds(gp, lp, 16, 0, 0);
}

// ---------------- CSR build ----------------
__global__ void k_init_counts(int* counts, int N) {
  int i = blockIdx.x * 256 + threadIdx.x;
  if (i < N) counts[i] = 1;  // self-loop
}

__global__ void k_count(const int* __restrict__ ei, int* counts, int E) {
  int i = blockIdx.x * 256 + threadIdx.x;
  if (i < E) atomicAdd(&counts[ei[E + i]], 1);
}

__global__ void k_scan(const int* __restrict__ counts, int* __restrict__ row_start,
                       int* __restrict__ cursor, int N) {
  __shared__ int sdata[1024];
  __shared__ int s_carry;
  int t = threadIdx.x;
  if (t == 0) s_carry = 0;
  __syncthreads();
  for (int base = 0; base < N; base += 1024) {
    int i = base + t;
    int v = (i < N) ? counts[i] : 0;
    sdata[t] = v;
    __syncthreads();
    for (int ofs = 1; ofs < 1024; ofs <<= 1) {
      int x = (t >= ofs) ? sdata[t - ofs] : 0;
      __syncthreads();
      sdata[t] += x;
      __syncthreads();
    }
    int carry = s_carry;
    if (i < N) {
      int excl = carry + sdata[t] - v;
      row_start[i] = excl;
      cursor[i] = excl;
    }
    __syncthreads();
    if (t == 1023) s_carry = carry + sdata[1023];
    __syncthreads();
  }
  if (t == 0) row_start[N] = s_carry;
}

__global__ void k_fill(const int* __restrict__ ei, int* cursor, int* __restrict__ csr_src,
                       int E, int N) {
  int i = blockIdx.x * 256 + threadIdx.x;
  if (i < E) {
    int s = ei[i], d = ei[E + i];
    int p = atomicAdd(&cursor[d], 1);
    csr_src[p] = s;
  } else if (i < E + N) {
    int n = i - E;
    int p = atomicAdd(&cursor[n], 1);
    csr_src[p] = n;
  }
}

// ---------------- split fp32 -> (hi, lo) bf16 ----------------
__global__ void k_split(const float* __restrict__ src, bf16* __restrict__ hi,
                        bf16* __restrict__ lo, int n) {
  int i = blockIdx.x * 256 + threadIdx.x;
  if (i < n) {
    float v = src[i];
    bf16 h = (bf16)v;
    hi[i] = h;
    lo[i] = (bf16)(v - (float)h);
  }
}

// W [256k,256n] row-major -> Wt hi/lo [n][k] bf16
__global__ void k_transpose_w(const float* __restrict__ W, bf16* __restrict__ Wth,
                              bf16* __restrict__ Wtl) {
  int k = blockIdx.x, n = threadIdx.x;
  float v = W[k * 256 + n];
  bf16 h = (bf16)v;
  Wth[n * 256 + k] = h;
  Wtl[n * 256 + k] = (bf16)(v - (float)h);
}

// ---------------- split-precision bf16 MFMA GEMM ----------------
// C[M,256] = A[M,256] @ Bt^T, A = Ah+Al, B = Bh+Bl (hi/lo bf16 planes), fp32 out.
__global__ __launch_bounds__(256) void k_gemm(
    const bf16* __restrict__ Ah, const bf16* __restrict__ Al,
    const bf16* __restrict__ Bh, const bf16* __restrict__ Bl,
    const float* __restrict__ bias, float* __restrict__ Cf, int M) {
  __shared__ bf16 Ash[128 * 32];
  __shared__ bf16 Asl[128 * 32];
  __shared__ bf16 Bsh[128 * 32];
  __shared__ bf16 Bsl[128 * 32];
  const int t = threadIdx.x;
  const int wave = t >> 6, lane = t & 63;
  const int m0 = blockIdx.x * 128, n0 = blockIdx.y * 128;
  const int lrow = lane & 15, lq = lane >> 4;
  const int wm = (wave >> 1) * 64, wn = (wave & 1) * 64;

  f32x4 acc[4][4] = {};

  // staging: 512 16B chunks per plane; chunk j -> row=j>>2, swizzled k-chunk
  const int j0 = wave * 64 + lane, j1 = j0 + 256;
  const int ar0 = j0 >> 2, ar1 = j1 >> 2;
  const int ak0 = ((j0 & 3) ^ ((ar0 >> 1) & 3)) * 8;
  const int ak1 = ((j1 & 3) ^ ((ar1 >> 1) & 3)) * 8;
  const int gm0 = min(m0 + ar0, M - 1), gm1 = min(m0 + ar1, M - 1);
  const size_t oa0 = (size_t)gm0 * 256 + ak0, oa1 = (size_t)gm1 * 256 + ak1;
  const size_t ob0 = (size_t)(n0 + ar0) * 256 + ak0, ob1 = (size_t)(n0 + ar1) * 256 + ak1;
  const int l0 = wave * 512, l1 = 2048 + wave * 512;

  for (int k0 = 0; k0 < 256; k0 += 32) {
    __syncthreads();
    gld_lds16(Ah + oa0 + k0, Ash + l0);
    gld_lds16(Ah + oa1 + k0, Ash + l1);
    gld_lds16(Al + oa0 + k0, Asl + l0);
    gld_lds16(Al + oa1 + k0, Asl + l1);
    gld_lds16(Bh + ob0 + k0, Bsh + l0);
    gld_lds16(Bh + ob1 + k0, Bsh + l1);
    gld_lds16(Bl + ob0 + k0, Bsl + l0);
    gld_lds16(Bl + ob1 + k0, Bsl + l1);
    __syncthreads();
    bf16x8 afh[4], afl[4], bfh[4], bfl[4];
#pragma unroll
    for (int mi = 0; mi < 4; mi++) {
      int row = wm + mi * 16 + lrow;
      int off = row * 32 + ((lq ^ ((row >> 1) & 3)) << 3);
      afh[mi] = *(const bf16x8*)(Ash + off);
      afl[mi] = *(const bf16x8*)(Asl + off);
    }
#pragma unroll
    for (int ni = 0; ni < 4; ni++) {
      int row = wn + ni * 16 + lrow;
      int off = row * 32 + ((lq ^ ((row >> 1) & 3)) << 3);
      bfh[ni] = *(const bf16x8*)(Bsh + off);
      bfl[ni] = *(const bf16x8*)(Bsl + off);
    }
#pragma unroll
    for (int mi = 0; mi < 4; mi++)
#pragma unroll
      for (int ni = 0; ni < 4; ni++) {
        acc[mi][ni] = __builtin_amdgcn_mfma_f32_16x16x32_bf16(afl[mi], bfh[ni], acc[mi][ni], 0, 0, 0);
        acc[mi][ni] = __builtin_amdgcn_mfma_f32_16x16x32_bf16(afh[mi], bfl[ni], acc[mi][ni], 0, 0, 0);
        acc[mi][ni] = __builtin_amdgcn_mfma_f32_16x16x32_bf16(afh[mi], bfh[ni], acc[mi][ni], 0, 0, 0);
      }
  }

#pragma unroll
  for (int mi = 0; mi < 4; mi++) {
    const int mb = m0 + wm + mi * 16 + lq * 4;
#pragma unroll
    for (int ni = 0; ni < 4; ni++) {
      const int n = n0 + wn + ni * 16 + lrow;
#pragma unroll
      for (int r = 0; r < 4; r++) {
        int m = mb + r;
        if (m < M)
          Cf[(size_t)m * 256 + n] = acc[mi][ni][r] + (bias ? bias[n] : 0.f);
      }
    }
  }
}

// ---------------- per-node attention scores al_s/al_d [N,4] (fp32 h) ----------------
__global__ __launch_bounds__(256) void k_al(
    const float* __restrict__ h, const float* __restrict__ asrc, const float* __restrict__ adst,
    float* __restrict__ als, float* __restrict__ ald, int N) {
  const int t = threadIdx.x;
  const float as = asrc[t], ad = adst[t];
  const int head = t >> 6;
  int nend = min(blockIdx.x * 4 + 4, N);
  for (int n = blockIdx.x * 4; n < nend; ++n) {
    float hv = h[(size_t)n * 256 + t];
    float vs = hv * as, vd = hv * ad;
    for (int o = 32; o > 0; o >>= 1) {
      vs += __shfl_down(vs, o, 64);
      vd += __shfl_down(vd, o, 64);
    }
    if ((t & 63) == 0) { als[n * 4 + head] = vs; ald[n * 4 + head] = vd; }
  }
}

// ---------------- per-dst softmax + aggregation (no atomics, fp32 h) ----------------
__global__ __launch_bounds__(256) void k_agg(
    const float* __restrict__ h, const float* __restrict__ als, const float* __restrict__ ald,
    const int* __restrict__ row_start, const int* __restrict__ csr_src,
    const float* __restrict__ bias, float* __restrict__ out, int N) {
  __shared__ float s_e[4][CHUNK];
  __shared__ int s_src[CHUNK];
  __shared__ float s_ald[4];
  const int t = threadIdx.x, head = t >> 6, lane = t & 63;
  const float bv = bias[t];
  int nend = min(blockIdx.x * 4 + 4, N);
  for (int n = blockIdx.x * 4; n < nend; ++n) {
    __syncthreads();
    if (t < 4) s_ald[t] = ald[n * 4 + t];
    __syncthreads();
    const float a0 = s_ald[0], a1 = s_ald[1], a2 = s_ald[2], a3 = s_ald[3];
    const int beg = row_start[n], end = row_start[n + 1];
    float m_run = -__builtin_inff(), s_run = 0.f, acc = 0.f;
    for (int c0 = beg; c0 < end; c0 += CHUNK) {
      const int cn = min(CHUNK, end - c0);
      __syncthreads();
      for (int i = t; i < cn; i += 256) {
        int s = csr_src[c0 + i];
        s_src[i] = s;
        const float4 av = *(const float4*)(als + s * 4);
        float e0 = av.x + a0, e1 = av.y + a1, e2 = av.z + a2, e3 = av.w + a3;
        s_e[0][i] = e0 > 0.f ? e0 : NEG_SLOPE * e0;
        s_e[1][i] = e1 > 0.f ? e1 : NEG_SLOPE * e1;
        s_e[2][i] = e2 > 0.f ? e2 : NEG_SLOPE * e2;
        s_e[3][i] = e3 > 0.f ? e3 : NEG_SLOPE * e3;
      }
      __syncthreads();
      float mloc = -__builtin_inff();
      for (int i = lane; i < cn; i += 64) mloc = fmaxf(mloc, s_e[head][i]);
      for (int o = 32; o > 0; o >>= 1) mloc = fmaxf(mloc, __shfl_xor(mloc, o, 64));
      const float mnew = fmaxf(m_run, mloc);
      const float scale = __expf(m_run - mnew);  // first chunk: exp(-inf)=0, acc=s=0 anyway
      acc *= scale; s_run *= scale;
      float ssum = 0.f;
      for (int i = lane; i < cn; i += 64) {
        float w = __expf(s_e[head][i] - mnew);
        s_e[head][i] = w;  // wave-local overwrite (head == wave id)
        ssum += w;
      }
      for (int o = 32; o > 0; o >>= 1) ssum += __shfl_xor(ssum, o, 64);
      s_run += ssum;
      m_run = mnew;
      const float* hp = h + t;
#pragma unroll 4
      for (int i = 0; i < cn; ++i) {
        acc += s_e[head][i] * hp[(size_t)s_src[i] * 256];
      }
    }
    out[(size_t)n * 256 + t] = acc / (s_run + 1e-16f) + bv;
  }
}

// ---------------- batch norm ----------------
__global__ void k_zero(float* p, int n) {
  int i = blockIdx.x * 256 + threadIdx.x;
  if (i < n) p[i] = 0.f;
}

__global__ __launch_bounds__(256) void k_bn_stats(const float* __restrict__ x,
                                                  float* __restrict__ stats, int N) {
  const int t = threadIdx.x;
  int r0 = blockIdx.x * 128;
  int rend = min(r0 + 128, N);
  float s = 0.f, sq = 0.f;
  for (int r = r0; r < rend; ++r) {
    float v = x[(size_t)r * 256 + t];
    s += v; sq += v * v;
  }
  atomicAdd(&stats[t], s);
  atomicAdd(&stats[256 + t], sq);
}

// l<2: write split bf16 activation (hi/lo). l==2: encf[idx] = relu(bn) + encf[idx] (in-place add).
__global__ __launch_bounds__(256) void k_bn_apply(
    const float* __restrict__ x, const float* __restrict__ stats,
    const float* __restrict__ g, const float* __restrict__ be,
    bf16* __restrict__ act_hi, bf16* __restrict__ act_lo, float* __restrict__ encf,
    float invN, int total) {
  int idx = blockIdx.x * 256 + threadIdx.x;
  if (idx >= total) return;
  int c = idx & 255;
  float mu = stats[c] * invN;
  float var = stats[256 + c] * invN - mu * mu;
  float v = (x[idx] - mu) * rsqrtf(var + BN_EPS) * g[c] + be[c];
  v = fmaxf(v, 0.f);
  if (act_hi) {
    bf16 h = (bf16)v;
    act_hi[idx] = h;
    act_lo[idx] = (bf16)(v - (float)h);
  }
  if (encf) encf[idx] = v + encf[idx];
}

// ---------------- VAE head: mu/logvar/z/out/aux ----------------
__global__ __launch_bounds__(256) void k_head(
    const float* __restrict__ enc, const float* __restrict__ eps,
    const float* __restrict__ Wmu, const float* __restrict__ bmu,
    const float* __restrict__ Wlv, const float* __restrict__ blv,
    const float* __restrict__ Wd, const float* __restrict__ bd,
    const float* __restrict__ Wa, const float* __restrict__ ba,
    float* __restrict__ o_out, float* __restrict__ o_mu, float* __restrict__ o_lv,
    float* __restrict__ o_aux, int N) {
  __shared__ float sE[8][256];
  __shared__ float sZ[8][32];
  const int t = threadIdx.x;
  const int r0 = blockIdx.x * 8;
#pragma unroll
  for (int r = 0; r < 8; ++r) {
    int rr = min(r0 + r, N - 1);
    sE[r][t] = enc[(size_t)rr * 256 + t];
  }
  __syncthreads();
  const int r = t >> 5, j = t & 31;
  const int row = r0 + r;
  float mu = bmu[j], lv = blv[j];
#pragma unroll 4
  for (int k = 0; k < 256; ++k) {
    float ev = sE[r][k];
    mu += ev * Wmu[k * 32 + j];
    lv += ev * Wlv[k * 32 + j];
  }
  float ep = (row < N) ? eps[(size_t)row * 32 + j] : 0.f;
  float z = mu + ep * __expf(0.5f * lv);
  sZ[r][j] = z;
  if (row < N) {
    o_mu[(size_t)row * 32 + j] = mu;
    o_lv[(size_t)row * 32 + j] = lv;
  }
  if (j < 30) {
    float ax = ba[j];
#pragma unroll 4
    for (int k = 0; k < 256; ++k) ax += sE[r][k] * Wa[k * 30 + j];
    if (row < N) o_aux[(size_t)row * 30 + j] = ax;
  }
  __syncthreads();
  float o = bd[j];
#pragma unroll
  for (int k = 0; k < 32; ++k) o += sZ[r][k] * Wd[k * 32 + j];
  if (row < N) o_out[(size_t)row * 32 + j] = o;
}

// ---------------- launcher ----------------
extern "C" void kernel_launch(void* const* d_in, const int* in_sizes, int n_in,
                              void* d_out, int out_size, void* d_ws, size_t ws_size,
                              hipStream_t stream) {
  const float* x   = (const float*)d_in[0];
  const int*   ei  = (const int*)d_in[1];
  const float* eps = (const float*)d_in[2];
  const float* Wg[3]   = {(const float*)d_in[3], (const float*)d_in[9],  (const float*)d_in[15]};
  const float* asrc[3] = {(const float*)d_in[4], (const float*)d_in[10], (const float*)d_in[16]};
  const float* adst[3] = {(const float*)d_in[5], (const float*)d_in[11], (const float*)d_in[17]};
  const float* bg[3]   = {(const float*)d_in[6], (const float*)d_in[12], (const float*)d_in[18]};
  const float* gam[3]  = {(const float*)d_in[7], (const float*)d_in[13], (const float*)d_in[19]};
  const float* bet[3]  = {(const float*)d_in[8], (const float*)d_in[14], (const float*)d_in[20]};
  const float* Wr  = (const float*)d_in[21];
  const float* br  = (const float*)d_in[22];
  const float* Wmu = (const float*)d_in[23];
  const float* bmu = (const float*)d_in[24];
  const float* Wlv = (const float*)d_in[25];
  const float* blv = (const float*)d_in[26];
  const float* Wd  = (const float*)d_in[27];
  const float* bd  = (const float*)d_in[28];
  const float* Wa  = (const float*)d_in[29];
  const float* ba  = (const float*)d_in[30];

  const int N = in_sizes[0] / 256;
  const int E = in_sizes[1] / 2;

  float* outp  = (float*)d_out;
  float* o_out = outp;
  float* o_mu  = outp + (size_t)N * 32;
  float* o_lv  = outp + (size_t)N * 64;
  float* o_aux = outp + (size_t)N * 96;
  float* o_enc = outp + (size_t)N * 96 + (size_t)N * 30;

  char* p = (char*)d_ws;
  auto carve = [&](size_t bytes) -> char* {
    char* r = p;
    p += (bytes + 255) & ~(size_t)255;
    return r;
  };
  int* counts    = (int*)carve((size_t)N * 4);
  int* row_start = (int*)carve(((size_t)N + 1) * 4);
  int* cursor    = (int*)carve((size_t)N * 4);
  int* csr_src   = (int*)carve((size_t)(E + N) * 4);
  bf16* Wth[4];
  bf16* Wtl[4];
  for (int i = 0; i < 4; ++i) {
    Wth[i] = (bf16*)carve(256 * 256 * 2);
    Wtl[i] = (bf16*)carve(256 * 256 * 2);
  }
  bf16* Ahi = (bf16*)carve((size_t)N * 256 * 2);  // activation hi (x, then layer acts)
  bf16* Alo = (bf16*)carve((size_t)N * 256 * 2);  // activation lo
  float* H   = (float*)carve((size_t)N * 256 * 4);  // h = act @ W  (fp32)
  float* AGG = (float*)carve((size_t)N * 256 * 4);
  float* als = (float*)carve((size_t)N * 4 * 4);
  float* ald = (float*)carve((size_t)N * 4 * 4);
  float* stats = (float*)carve(512 * 4);

  dim3 b256(256);

  // CSR by dst (self-loops included as count init = 1)
  k_init_counts<<<(N + 255) / 256, b256, 0, stream>>>(counts, N);
  k_count<<<(E + 255) / 256, b256, 0, stream>>>(ei, counts, E);
  k_scan<<<1, 1024, 0, stream>>>(counts, row_start, cursor, N);
  k_fill<<<(E + N + 255) / 256, b256, 0, stream>>>(ei, cursor, csr_src, E, N);

  // conversions: x -> hi/lo split; weights -> transposed hi/lo
  k_split<<<((size_t)N * 256 + 255) / 256, b256, 0, stream>>>(x, Ahi, Alo, N * 256);
  k_transpose_w<<<256, b256, 0, stream>>>(Wr, Wth[0], Wtl[0]);
  for (int l = 0; l < 3; ++l)
    k_transpose_w<<<256, b256, 0, stream>>>(Wg[l], Wth[l + 1], Wtl[l + 1]);

  dim3 ggrid((N + 127) / 128, 2);
  // residual = x @ Wr + br -> o_enc (bn3 adds relu(bn) in-place later)
  k_gemm<<<ggrid, b256, 0, stream>>>(Ahi, Alo, Wth[0], Wtl[0], br, o_enc, N);

  const float invN = 1.0f / (float)N;
  for (int l = 0; l < 3; ++l) {
    k_gemm<<<ggrid, b256, 0, stream>>>(Ahi, Alo, Wth[l + 1], Wtl[l + 1], nullptr, H, N);
    k_al<<<(N + 3) / 4, b256, 0, stream>>>(H, asrc[l], adst[l], als, ald, N);
    k_zero<<<2, b256, 0, stream>>>(stats, 512);
    k_agg<<<(N + 3) / 4, b256, 0, stream>>>(H, als, ald, row_start, csr_src, bg[l], AGG, N);
    k_bn_stats<<<(N + 127) / 128, b256, 0, stream>>>(AGG, stats, N);
    if (l < 2)
      k_bn_apply<<<((size_t)N * 256 + 255) / 256, b256, 0, stream>>>(
          AGG, stats, gam[l], bet[l], Ahi, Alo, nullptr, invN, N * 256);
    else
      k_bn_apply<<<((size_t)N * 256 + 255) / 256, b256, 0, stream>>>(
          AGG, stats, gam[l], bet[l], nullptr, nullptr, o_enc, invN, N * 256);
  }

  k_head<<<(N + 7) / 8, b256, 0, stream>>>(o_enc, eps, Wmu, bmu, Wlv, blv, Wd, bd, Wa, ba,
                                           o_out, o_mu, o_lv, o_aux, N);
}